// Round 7
// baseline (40620.184 us; speedup 1.0000x reference)
//
#include <hip/hip_runtime.h>

#define Hh 160
#define Ww 400
#define Cc 256
#define HW 64000

__device__ __forceinline__ float sigclip(float v) {
    const float s = 1.0f / (1.0f + expf(-v));
    return fminf(fmaxf(s, 1e-4f), 1.0f - 1e-4f);
}

// ---------------------------------------------------------------------------
// Conv3x3(256->256)+b+ReLU+Conv1x1(256->cout)+b for ONE head. FLOAT32 in/out.
// (R0-R6 forensics: d_out is 896000 floats; inputs are fp32 buffers holding
//  bf16-rounded values. Earlier rounds' u16 stores packed 2 outputs per float
//  slot -> float-window 3 showed y-coordinate composites, err 159.369.)
// Block = one 64-px row tile; thread (g=tid/64, px=tid%64) accumulates hidden
// channels [g*64,(g+1)*64) for pixel px; 4-way LDS reduce through the 1x1.
// ---------------------------------------------------------------------------
__global__ __launch_bounds__(256) void conv_head_simple(
    const float* __restrict__ x,
    const float* __restrict__ w1, const float* __restrict__ b1,
    const float* __restrict__ w2, const float* __restrict__ b2,
    float* __restrict__ out, int outoff, int cout, int apply_sig)
{
    const int px = threadIdx.x & 63;
    const int g  = threadIdx.x >> 6;
    const int x0 = blockIdx.x * 64;
    const int y  = blockIdx.y;
    const int xg = x0 + px;

    __shared__ float Red[4][64][2];

    bool valid[9];
    int  xoff[9];
    #pragma unroll
    for (int dy = 0; dy < 3; ++dy) {
        const int yy = y + dy - 1;
        #pragma unroll
        for (int dx = 0; dx < 3; ++dx) {
            const int xx = xg + dx - 1;
            const int k = dy * 3 + dx;
            valid[k] = (yy >= 0 && yy < Hh && xx >= 0 && xx < Ww);
            xoff[k]  = valid[k] ? (yy * Ww + xx) : 0;
        }
    }

    float hid[64];
    #pragma unroll
    for (int mi = 0; mi < 64; ++mi) hid[mi] = b1[g * 64 + mi];

    for (int ci = 0; ci < Cc; ++ci) {
        const float* xch = x + (size_t)ci * HW;
        float xv[9];
        #pragma unroll
        for (int k = 0; k < 9; ++k) xv[k] = valid[k] ? xch[xoff[k]] : 0.0f;

        const float* wci = w1 + ((size_t)(g * 64) * Cc + ci) * 9;
        #pragma unroll 8
        for (int mi = 0; mi < 64; ++mi) {
            const float* wr = wci + (size_t)mi * (Cc * 9);
            float h = hid[mi];
            #pragma unroll
            for (int k = 0; k < 9; ++k) h = fmaf(wr[k], xv[k], h);
            hid[mi] = h;
        }
    }

    float p0 = 0.0f, p1 = 0.0f;
    #pragma unroll 8
    for (int mi = 0; mi < 64; ++mi) {
        const int m = g * 64 + mi;
        const float h = fmaxf(hid[mi], 0.0f);
        p0 = fmaf(w2[m], h, p0);
        if (cout == 2) p1 = fmaf(w2[Cc + m], h, p1);
    }
    Red[g][px][0] = p0;
    Red[g][px][1] = p1;
    __syncthreads();

    if (g == 0 && xg < Ww) {
        for (int c = 0; c < cout; ++c) {
            float s = b2[c] + Red[0][px][c] + Red[1][px][c]
                            + Red[2][px][c] + Red[3][px][c];
            if (apply_sig) s = sigclip(s);
            out[outoff + c * HW + y * Ww + xg] = s;
        }
    }
}

// ---------------------------------------------------------------------------
// Decode: reads fp32 maps [HW,6HW) written by the convs, writes [6HW,14HW).
// Float-element layout (return order, 896000 total):
//   hm@0 kpts@HW pts@2HW int@4HW heat@6HW mask_low@7HW root@8HW align@10HW
//   kpt_mask@12HW
// ---------------------------------------------------------------------------
__global__ __launch_bounds__(256) void finalize_decode(float* __restrict__ out)
{
    const int i = blockIdx.x * 256 + threadIdx.x;
    if (i >= HW) return;
    const int h = i / Ww;
    const int w = i - h * Ww;

    const float k0 = out[HW + i];
    const float km = (w > 0)      ? out[HW + i - 1] : -1e30f;
    const float kp = (w < Ww - 1) ? out[HW + i + 1] : -1e30f;
    const float hmax = fmaxf(km, fmaxf(k0, kp));
    const float heat = (hmax == k0) ? k0 : 0.0f;

    const float off0 = out[2 * HW + i];
    const float off1 = out[3 * HW + i];
    const float reg0 = out[4 * HW + i];
    const float reg1 = out[5 * HW + i];

    const bool kmask = heat > 0.4f;

    out[6 * HW + i] = heat;
    out[7 * HW + w * Hh + h] = (off1 < 1.0f && kmask) ? 1.0f : 0.0f;
    out[8 * HW + 2 * i]      = (float)w + off0;
    out[8 * HW + 2 * i + 1]  = (float)h + off1;
    out[10 * HW + 2 * i]     = (float)w + reg0;
    out[10 * HW + 2 * i + 1] = (float)h + reg1;
    const float kb = kmask ? 1.0f : 0.0f;
    out[12 * HW + 2 * i]     = kb;
    out[12 * HW + 2 * i + 1] = kb;
}

// ---------------------------------------------------------------------------
extern "C" void kernel_launch(void* const* d_in, const int* in_sizes, int n_in,
                              void* d_out, int out_size, void* d_ws, size_t ws_size,
                              hipStream_t stream) {
    (void)in_sizes; (void)n_in; (void)d_ws; (void)ws_size; (void)out_size;

    const float* x = (const float*)d_in[0];
    float* out = (float*)d_out;

    const int outoffs[4] = {0, HW, 2 * HW, 4 * HW};
    const int couts[4]   = {1, 1, 2, 2};
    for (int hd = 0; hd < 4; ++hd) {
        conv_head_simple<<<dim3(7, 160), 256, 0, stream>>>(
            x,
            (const float*)d_in[1 + 4 * hd], (const float*)d_in[2 + 4 * hd],
            (const float*)d_in[3 + 4 * hd], (const float*)d_in[4 + 4 * hd],
            out, outoffs[hd], couts[hd], (hd < 2) ? 1 : 0);
    }
    finalize_decode<<<dim3(250), 256, 0, stream>>>(out);
}

// Round 8
// 1212.132 us; speedup vs baseline: 33.5114x; 33.5114x over previous
//
#include <hip/hip_runtime.h>

#define Hh 160
#define Ww 400
#define Cc 256
#define HW 64000

typedef unsigned short u16;
typedef unsigned int   u32;
typedef __attribute__((ext_vector_type(8))) short short8;
typedef __attribute__((ext_vector_type(4))) float f32x4;

#define WA_STRIDE 40                       // u16 per m-row: 32 kk + 8 pad (80B, 16B-aligned, odd dword stride)
#define WA_U16    (4*72*256*WA_STRIDE)     // 2,949,120 u16 = 5,898,240 B
#define GUARD_ROWS 512
#define GUARD     (GUARD_ROWS*256)         // u16 per side
#define WS_NEED   (WA_U16*2 + (2*GUARD + HW*256)*2)   // 39,190,528 B

__device__ __forceinline__ u16 f2b(float v) {
    const u32 u = __float_as_uint(v);
    return (u16)((u + 0x7FFFu + ((u >> 16) & 1u)) >> 16);
}
__device__ __forceinline__ float sigclip(float v) {
    const float s = 1.0f / (1.0f + expf(-v));
    return fminf(fmaxf(s, 1e-4f), 1.0f - 1e-4f);
}

// ---------------------------------------------------------------------------
// Prep 1: weight image. Wa[head][s][m][WA_STRIDE], s = tap*8 + cib:
//   Wa[...][m][kk] = bf16( w1[m][cib*32+kk][tap] ), pads zeroed.
// ---------------------------------------------------------------------------
__global__ __launch_bounds__(256) void prep_weights(
    const float* __restrict__ w0, const float* __restrict__ w1p,
    const float* __restrict__ w2p, const float* __restrict__ w3p,
    u16* __restrict__ Wa)
{
    const int hs   = blockIdx.x;          // head*72 + s
    const int head = hs / 72;
    const int s    = hs - head * 72;
    const int tap  = s >> 3;
    const int cib  = s & 7;
    const float* w = head == 0 ? w0 : head == 1 ? w1p : head == 2 ? w2p : w3p;
    const int m = threadIdx.x;
    u16* dst = Wa + ((size_t)hs * 256 + m) * WA_STRIDE;
    const float* src = w + (size_t)m * (Cc * 9) + (size_t)(cib * 32) * 9 + tap;
    #pragma unroll
    for (int kk = 0; kk < 32; ++kk) dst[kk] = f2b(src[kk * 9]);
    #pragma unroll
    for (int kk = 32; kk < WA_STRIDE; ++kk) dst[kk] = 0;
}

// ---------------------------------------------------------------------------
// Prep 2: x (fp32 [ci][p]) -> xt (bf16 [p][ci]), ci contiguous. L2 merges the
// strided dword writes (each 64B line is filled across 16 consecutive iters).
// ---------------------------------------------------------------------------
__global__ __launch_bounds__(256) void prep_x(
    const float* __restrict__ x, u32* __restrict__ xt32)
{
    const int p = blockIdx.x * 256 + threadIdx.x;   // 250 blocks -> exactly HW
    #pragma unroll 4
    for (int cip = 0; cip < 128; ++cip) {
        const float a = x[(size_t)(2 * cip) * HW + p];
        const float b = x[(size_t)(2 * cip + 1) * HW + p];
        xt32[(size_t)p * 128 + cip] = (u32)f2b(a) | ((u32)f2b(b) << 16);
    }
}

// Prep 3: zero the guard rows on both sides of xt.
__global__ __launch_bounds__(256) void prep_guard(uint4* front, uint4* back)
{
    const int i = blockIdx.x * 256 + threadIdx.x;   // GUARD/8 = 16384 uint4/side
    const uint4 z = {0u, 0u, 0u, 0u};
    if (i < GUARD / 8) { front[i] = z; back[i] = z; }
}

// ---------------------------------------------------------------------------
// MFMA conv: per block: M-tile 128 (mt half of 256), N-tile 128 = 64 px x 2
// rows, K = 2304 in 72 steps of 32 (tap-major, ci-blocks inner).
// 4 waves: wave (mblk = wv>>1) m-half, (nblk = wv&1) row-half; each 64x64 as
// 4x4 frags of mfma_f32_16x16x32_bf16 (acc 64 VGPR).
// A from LDS (copied per step, conflict-free 17-dword stride);
// B direct dwordx4 from xt (guards cover all shifted addresses; borders
// zeroed by cndmask). Epilogue: bias+ReLU+1x1(+sigmoid) via LDS reduce.
// ---------------------------------------------------------------------------
__global__ __launch_bounds__(256) void conv_mfma(
    const u16* __restrict__ Wa, const u16* __restrict__ xt,
    const float* __restrict__ b1_0, const float* __restrict__ b1_1,
    const float* __restrict__ b1_2, const float* __restrict__ b1_3,
    const float* __restrict__ w2_0, const float* __restrict__ w2_1,
    const float* __restrict__ w2_2, const float* __restrict__ w2_3,
    const float* __restrict__ b2_0, const float* __restrict__ b2_1,
    const float* __restrict__ b2_2, const float* __restrict__ b2_3,
    float* __restrict__ out)
{
    __shared__ u16   As[128 * WA_STRIDE];     // 10,240 B
    __shared__ float Red[128][2][8];          //  8,192 B

    const int t    = threadIdx.x;
    const int lane = t & 63, wv = t >> 6;
    const int q    = lane >> 4, n16 = lane & 15;
    const int x0   = blockIdx.x * 64;
    const int y0   = blockIdx.y * 2;
    const int head = blockIdx.z >> 1;
    const int mt   = blockIdx.z & 1;
    const int nblk = wv & 1;                  // row half
    const int mblk = wv >> 1;                 // m half (64) within the 128-tile
    const int ry   = y0 + nblk;               // this wave's pixel row

    f32x4 acc[4][4];
    #pragma unroll
    for (int mi = 0; mi < 4; ++mi)
        #pragma unroll
        for (int nj = 0; nj < 4; ++nj) {
            f32x4 z = {0.f, 0.f, 0.f, 0.f};
            acc[mi][nj] = z;
        }

    const u16* WaBase = Wa + ((size_t)(head * 72) * 256 + (size_t)mt * 128) * WA_STRIDE;

    for (int s = 0; s < 72; ++s) {
        const int tap = s >> 3, cib = s & 7;
        const int ky = tap / 3, kx = tap - ky * 3;

        // --- B fragments: direct global dwordx4 from xt (issued early)
        uint4 bv[4];
        const int  yr    = ry + ky - 1;
        const bool rowok = (yr >= 0) && (yr < Hh);
        #pragma unroll
        for (int nj = 0; nj < 4; ++nj) {
            const int  xc = x0 + nj * 16 + n16 + kx - 1;
            const bool ok = rowok && (xc >= 0) && (xc < Ww);
            const long p  = (long)yr * Ww + xc;            // within +/-GUARD_ROWS
            uint4 v = *(const uint4*)(xt + p * 256 + (cib * 32 + q * 8));
            v.x = ok ? v.x : 0u;  v.y = ok ? v.y : 0u;
            v.z = ok ? v.z : 0u;  v.w = ok ? v.w : 0u;
            bv[nj] = v;
        }

        __syncthreads();                       // prior step's a-frag reads done
        {   // --- stage A tile: 10,240 B = 640 uint4
            const uint4* src4 = (const uint4*)(WaBase + (size_t)s * 256 * WA_STRIDE);
            uint4* dst4 = (uint4*)As;
            #pragma unroll
            for (int i = t; i < 640; i += 256) dst4[i] = src4[i];
        }
        __syncthreads();

        #pragma unroll
        for (int mi = 0; mi < 4; ++mi) {
            const short8 a =
                *(const short8*)&As[(mblk * 64 + mi * 16 + n16) * WA_STRIDE + q * 8];
            #pragma unroll
            for (int nj = 0; nj < 4; ++nj) {
                const short8 b = __builtin_bit_cast(short8, bv[nj]);
                acc[mi][nj] =
                    __builtin_amdgcn_mfma_f32_16x16x32_bf16(a, b, acc[mi][nj], 0, 0, 0);
            }
        }
    }

    // --- epilogue: bias + ReLU + 1x1 partials in-lane, then LDS reduce
    const float* b1 = head == 0 ? b1_0 : head == 1 ? b1_1 : head == 2 ? b1_2 : b1_3;
    const float* w2 = head == 0 ? w2_0 : head == 1 ? w2_1 : head == 2 ? w2_2 : w2_3;
    const float* b2 = head == 0 ? b2_0 : head == 1 ? b2_1 : head == 2 ? b2_2 : b2_3;
    const int cout   = (head < 2) ? 1 : 2;
    const int outoff = head == 0 ? 0 : head == 1 ? HW : head == 2 ? 2 * HW : 4 * HW;

    float p0[4] = {0.f, 0.f, 0.f, 0.f}, p1[4] = {0.f, 0.f, 0.f, 0.f};
    #pragma unroll
    for (int mi = 0; mi < 4; ++mi)
        #pragma unroll
        for (int r = 0; r < 4; ++r) {
            const int m = mt * 128 + mblk * 64 + mi * 16 + q * 4 + r;
            const float bb = b1[m], wc0 = w2[m];
            const float wc1 = (cout == 2) ? w2[Cc + m] : 0.0f;
            #pragma unroll
            for (int nj = 0; nj < 4; ++nj) {
                const float h = fmaxf(acc[mi][nj][r] + bb, 0.0f);
                p0[nj] = fmaf(wc0, h, p0[nj]);
                p1[nj] = fmaf(wc1, h, p1[nj]);
            }
        }

    __syncthreads();
    #pragma unroll
    for (int nj = 0; nj < 4; ++nj) {
        const int n = nblk * 64 + nj * 16 + n16;
        Red[n][0][mblk * 4 + q] = p0[nj];
        Red[n][1][mblk * 4 + q] = p1[nj];
    }
    __syncthreads();

    if (t < cout * 128) {
        const int n = t & 127, c = t >> 7;
        float sv = b2[c];
        #pragma unroll
        for (int i = 0; i < 8; ++i) sv += Red[n][c][i];
        if (head < 2) sv = sigclip(sv);
        const int xg = x0 + (n & 63);
        const int yg = y0 + (n >> 6);
        if (xg < Ww) out[outoff + c * HW + yg * Ww + xg] = sv;
    }
}

// ---------------------------------------------------------------------------
// Fallback conv (R7, known-green, slow) if ws is too small for the fast path.
// ---------------------------------------------------------------------------
__global__ __launch_bounds__(256) void conv_head_simple(
    const float* __restrict__ x,
    const float* __restrict__ w1, const float* __restrict__ b1,
    const float* __restrict__ w2, const float* __restrict__ b2,
    float* __restrict__ out, int outoff, int cout, int apply_sig)
{
    const int px = threadIdx.x & 63;
    const int g  = threadIdx.x >> 6;
    const int x0 = blockIdx.x * 64;
    const int y  = blockIdx.y;
    const int xg = x0 + px;
    __shared__ float RedS[4][64][2];

    bool valid[9]; int xoff[9];
    #pragma unroll
    for (int dy = 0; dy < 3; ++dy) {
        const int yy = y + dy - 1;
        #pragma unroll
        for (int dx = 0; dx < 3; ++dx) {
            const int xx = xg + dx - 1;
            const int k = dy * 3 + dx;
            valid[k] = (yy >= 0 && yy < Hh && xx >= 0 && xx < Ww);
            xoff[k]  = valid[k] ? (yy * Ww + xx) : 0;
        }
    }
    float hid[64];
    #pragma unroll
    for (int mi = 0; mi < 64; ++mi) hid[mi] = b1[g * 64 + mi];
    for (int ci = 0; ci < Cc; ++ci) {
        const float* xch = x + (size_t)ci * HW;
        float xv[9];
        #pragma unroll
        for (int k = 0; k < 9; ++k) xv[k] = valid[k] ? xch[xoff[k]] : 0.0f;
        const float* wci = w1 + ((size_t)(g * 64) * Cc + ci) * 9;
        #pragma unroll 8
        for (int mi = 0; mi < 64; ++mi) {
            const float* wr = wci + (size_t)mi * (Cc * 9);
            float h = hid[mi];
            #pragma unroll
            for (int k = 0; k < 9; ++k) h = fmaf(wr[k], xv[k], h);
            hid[mi] = h;
        }
    }
    float p0 = 0.f, p1 = 0.f;
    #pragma unroll 8
    for (int mi = 0; mi < 64; ++mi) {
        const int m = g * 64 + mi;
        const float h = fmaxf(hid[mi], 0.0f);
        p0 = fmaf(w2[m], h, p0);
        if (cout == 2) p1 = fmaf(w2[Cc + m], h, p1);
    }
    RedS[g][px][0] = p0; RedS[g][px][1] = p1;
    __syncthreads();
    if (g == 0 && xg < Ww)
        for (int c = 0; c < cout; ++c) {
            float sv = b2[c] + RedS[0][px][c] + RedS[1][px][c]
                             + RedS[2][px][c] + RedS[3][px][c];
            if (apply_sig) sv = sigclip(sv);
            out[outoff + c * HW + y * Ww + xg] = sv;
        }
}

// ---------------------------------------------------------------------------
// Decode (unchanged, green): reads [HW,6HW), writes [6HW,14HW).
// ---------------------------------------------------------------------------
__global__ __launch_bounds__(256) void finalize_decode(float* __restrict__ out)
{
    const int i = blockIdx.x * 256 + threadIdx.x;
    if (i >= HW) return;
    const int h = i / Ww;
    const int w = i - h * Ww;

    const float k0 = out[HW + i];
    const float km = (w > 0)      ? out[HW + i - 1] : -1e30f;
    const float kp = (w < Ww - 1) ? out[HW + i + 1] : -1e30f;
    const float hmax = fmaxf(km, fmaxf(k0, kp));
    const float heat = (hmax == k0) ? k0 : 0.0f;

    const float off0 = out[2 * HW + i];
    const float off1 = out[3 * HW + i];
    const float reg0 = out[4 * HW + i];
    const float reg1 = out[5 * HW + i];
    const bool kmask = heat > 0.4f;

    out[6 * HW + i] = heat;
    out[7 * HW + w * Hh + h] = (off1 < 1.0f && kmask) ? 1.0f : 0.0f;
    out[8 * HW + 2 * i]      = (float)w + off0;
    out[8 * HW + 2 * i + 1]  = (float)h + off1;
    out[10 * HW + 2 * i]     = (float)w + reg0;
    out[10 * HW + 2 * i + 1] = (float)h + reg1;
    const float kb = kmask ? 1.0f : 0.0f;
    out[12 * HW + 2 * i]     = kb;
    out[12 * HW + 2 * i + 1] = kb;
}

// ---------------------------------------------------------------------------
extern "C" void kernel_launch(void* const* d_in, const int* in_sizes, int n_in,
                              void* d_out, int out_size, void* d_ws, size_t ws_size,
                              hipStream_t stream) {
    (void)in_sizes; (void)n_in; (void)out_size;
    const float* x = (const float*)d_in[0];
    float* out = (float*)d_out;

    if (ws_size >= (size_t)WS_NEED) {
        u16* Wa       = (u16*)d_ws;
        u16* xt_alloc = Wa + WA_U16;          // 16B-aligned (WA_U16*2 % 16 == 0)
        u16* xt       = xt_alloc + GUARD;     // xt[p*256 + ci], p in [0,HW)

        prep_weights<<<dim3(288), 256, 0, stream>>>(
            (const float*)d_in[1], (const float*)d_in[5],
            (const float*)d_in[9], (const float*)d_in[13], Wa);
        prep_x<<<dim3(250), 256, 0, stream>>>(x, (u32*)xt);
        prep_guard<<<dim3(64), 256, 0, stream>>>(
            (uint4*)xt_alloc, (uint4*)(xt + (size_t)HW * 256));

        conv_mfma<<<dim3(7, 80, 8), 256, 0, stream>>>(
            Wa, xt,
            (const float*)d_in[2],  (const float*)d_in[6],
            (const float*)d_in[10], (const float*)d_in[14],
            (const float*)d_in[3],  (const float*)d_in[7],
            (const float*)d_in[11], (const float*)d_in[15],
            (const float*)d_in[4],  (const float*)d_in[8],
            (const float*)d_in[12], (const float*)d_in[16],
            out);
    } else {
        const int outoffs[4] = {0, HW, 2 * HW, 4 * HW};
        const int couts[4]   = {1, 1, 2, 2};
        for (int hd = 0; hd < 4; ++hd)
            conv_head_simple<<<dim3(7, 160), 256, 0, stream>>>(
                x,
                (const float*)d_in[1 + 4 * hd], (const float*)d_in[2 + 4 * hd],
                (const float*)d_in[3 + 4 * hd], (const float*)d_in[4 + 4 * hd],
                out, outoffs[hd], couts[hd], (hd < 2) ? 1 : 0);
    }
    finalize_decode<<<dim3(250), 256, 0, stream>>>(out);
}

// Round 9
// 893.949 us; speedup vs baseline: 45.4390x; 1.3559x over previous
//
#include <hip/hip_runtime.h>

#define Hh 160
#define Ww 400
#define Cc 256
#define HW 64000

typedef unsigned short u16;
typedef unsigned int   u32;
typedef __attribute__((ext_vector_type(8))) short short8;
typedef __attribute__((ext_vector_type(4))) float f32x4;

// Wa2: weights pre-arranged in MFMA A-fragment order.
// index = (((hm*72 + s)*2 + mblk)*4 + mi)*512 + lane*8, hm = head*2+mt,
// s = cib*9 + tap (ci-block major -> 9-tap L1 reuse window in main loop),
// element j of lane (q*16+n16): A[m = mt*128+mblk*64+mi*16+n16][ci = cib*32+q*8+j][tap]
#define WA2_U16   (8*72*2*4*512)           // 2,359,296 u16 = 4,718,592 B
#define GUARD_ROWS 512
#define GUARD     (GUARD_ROWS*256)         // u16 per side
#define WS_NEED   (WA2_U16*2 + (2*GUARD + HW*256)*2)   // 38,010,880 B

__device__ __forceinline__ u16 f2b(float v) {
    const u32 u = __float_as_uint(v);
    return (u16)((u + 0x7FFFu + ((u >> 16) & 1u)) >> 16);
}
__device__ __forceinline__ float sigclip(float v) {
    const float s = 1.0f / (1.0f + expf(-v));
    return fminf(fmaxf(s, 1e-4f), 1.0f - 1e-4f);
}

// ---------------------------------------------------------------------------
// Prep 1: weights -> MFMA fragment-ordered image (one block per (head,s)).
// ---------------------------------------------------------------------------
__global__ __launch_bounds__(256) void prep_weights(
    const float* __restrict__ w0, const float* __restrict__ w1p,
    const float* __restrict__ w2p, const float* __restrict__ w3p,
    u16* __restrict__ Wa2)
{
    const int blk  = blockIdx.x;           // head*72 + s
    const int head = blk / 72;
    const int s    = blk - head * 72;
    const int cib  = s / 9;
    const int tap  = s - cib * 9;
    const float* w = head == 0 ? w0 : head == 1 ? w1p : head == 2 ? w2p : w3p;

    const int t    = threadIdx.x;          // (((mt*2+mblk)*4+mi)*16 + n16)
    const int n16  = t & 15;
    const int mi   = (t >> 4) & 3;
    const int mblk = (t >> 6) & 1;
    const int mt   = t >> 7;
    const int m    = mt * 128 + mblk * 64 + mi * 16 + n16;
    const int hm   = head * 2 + mt;

    uint4* dst4 = (uint4*)Wa2 +
        ((size_t)((hm * 72 + s) * 2 + mblk) * 4 + mi) * 64 + n16;
    #pragma unroll
    for (int qq = 0; qq < 4; ++qq) {
        u16 tmp[8];
        #pragma unroll
        for (int j = 0; j < 8; ++j) {
            const int ci = cib * 32 + qq * 8 + j;
            tmp[j] = f2b(w[(size_t)m * (Cc * 9) + (size_t)ci * 9 + tap]);
        }
        dst4[qq * 16] = *(const uint4*)tmp;
    }
}

// ---------------------------------------------------------------------------
// Prep 2: x (fp32 [ci][p]) -> xt (bf16 [p][ci]).
// ---------------------------------------------------------------------------
__global__ __launch_bounds__(256) void prep_x(
    const float* __restrict__ x, u32* __restrict__ xt32)
{
    const int p = blockIdx.x * 256 + threadIdx.x;   // 250 blocks = HW exactly
    #pragma unroll 4
    for (int cip = 0; cip < 128; ++cip) {
        const float a = x[(size_t)(2 * cip) * HW + p];
        const float b = x[(size_t)(2 * cip + 1) * HW + p];
        xt32[(size_t)p * 128 + cip] = (u32)f2b(a) | ((u32)f2b(b) << 16);
    }
}

// Prep 3: zero guard rows on both sides of xt.
__global__ __launch_bounds__(256) void prep_guard(uint4* front, uint4* back)
{
    const int i = blockIdx.x * 256 + threadIdx.x;   // GUARD/8 = 16384 per side
    const uint4 z = {0u, 0u, 0u, 0u};
    if (i < GUARD / 8) { front[i] = z; back[i] = z; }
}

// ---------------------------------------------------------------------------
// MFMA conv, BARRIER-FREE K-loop: A-frags direct coalesced global loads from
// fragment-ordered Wa2 (L2-resident), B-frags direct from xt (L1-reused over
// the 9-tap window, ci-block-major order). No LDS until the epilogue.
// Block: 128m x (64px x 2rows); 4 waves = (mblk, nblk); wave tile 64x64 as
// 4x4 frags of mfma_f32_16x16x32_bf16.
// ---------------------------------------------------------------------------
__global__ __launch_bounds__(256) void conv_mfma(
    const u16* __restrict__ Wa2, const u16* __restrict__ xt,
    const float* __restrict__ b1_0, const float* __restrict__ b1_1,
    const float* __restrict__ b1_2, const float* __restrict__ b1_3,
    const float* __restrict__ w2_0, const float* __restrict__ w2_1,
    const float* __restrict__ w2_2, const float* __restrict__ w2_3,
    const float* __restrict__ b2_0, const float* __restrict__ b2_1,
    const float* __restrict__ b2_2, const float* __restrict__ b2_3,
    float* __restrict__ out)
{
    __shared__ float Red[128][2][8];          // 8 KB

    const int t    = threadIdx.x;
    const int lane = t & 63, wv = t >> 6;
    const int q    = lane >> 4, n16 = lane & 15;
    const int x0   = blockIdx.x * 64;
    const int y0   = blockIdx.y * 2;
    const int hm   = blockIdx.z;              // head*2 + mt
    const int head = hm >> 1;
    const int mt   = hm & 1;
    const int nblk = wv & 1;
    const int mblk = wv >> 1;

    f32x4 acc[4][4];
    #pragma unroll
    for (int mi = 0; mi < 4; ++mi)
        #pragma unroll
        for (int nj = 0; nj < 4; ++nj) {
            f32x4 z = {0.f, 0.f, 0.f, 0.f};
            acc[mi][nj] = z;
        }

    const u16* aw = Wa2 + (size_t)hm * (72 * 4096) + (size_t)mblk * 2048
                        + (size_t)lane * 8;
    const long prow = (long)(y0 + nblk - 1) * Ww + (x0 + n16 - 1);
    const u16* bw = xt + prow * 256 + q * 8;

    // hoisted border masks
    bool okx[4][3], oky[3];
    #pragma unroll
    for (int nj = 0; nj < 4; ++nj)
        #pragma unroll
        for (int kx = 0; kx < 3; ++kx) {
            const int xc = x0 + nj * 16 + n16 + kx - 1;
            okx[nj][kx] = (xc >= 0) && (xc < Ww);
        }
    #pragma unroll
    for (int ky = 0; ky < 3; ++ky) {
        const int yr = y0 + nblk + ky - 1;
        oky[ky] = (yr >= 0) && (yr < Hh);
    }

    for (int cib = 0; cib < 8; ++cib) {
        const u16* acb = aw + (size_t)cib * (9 * 4096);
        const u16* bcb = bw + cib * 32;
        #pragma unroll
        for (int tap = 0; tap < 9; ++tap) {
            const int ky = tap / 3, kx = tap - ky * 3;     // compile-time
            short8 a[4];
            #pragma unroll
            for (int mi = 0; mi < 4; ++mi)
                a[mi] = *(const short8*)(acb + tap * 4096 + mi * 512);
            #pragma unroll
            for (int nj = 0; nj < 4; ++nj) {
                uint4 v = *(const uint4*)(bcb + (ky * Ww + kx) * 256 + nj * 4096);
                const bool ok = oky[ky] && okx[nj][kx];
                v.x = ok ? v.x : 0u;  v.y = ok ? v.y : 0u;
                v.z = ok ? v.z : 0u;  v.w = ok ? v.w : 0u;
                const short8 b = __builtin_bit_cast(short8, v);
                #pragma unroll
                for (int mi = 0; mi < 4; ++mi)
                    acc[mi][nj] = __builtin_amdgcn_mfma_f32_16x16x32_bf16(
                        a[mi], b, acc[mi][nj], 0, 0, 0);
            }
        }
    }

    // --- epilogue: bias + ReLU + 1x1 partials, LDS reduce (single barrier)
    const float* b1 = head == 0 ? b1_0 : head == 1 ? b1_1 : head == 2 ? b1_2 : b1_3;
    const float* w2 = head == 0 ? w2_0 : head == 1 ? w2_1 : head == 2 ? w2_2 : w2_3;
    const float* b2 = head == 0 ? b2_0 : head == 1 ? b2_1 : head == 2 ? b2_2 : b2_3;
    const int cout   = (head < 2) ? 1 : 2;
    const int outoff = head == 0 ? 0 : head == 1 ? HW : head == 2 ? 2 * HW : 4 * HW;

    float p0[4] = {0.f, 0.f, 0.f, 0.f}, p1[4] = {0.f, 0.f, 0.f, 0.f};
    #pragma unroll
    for (int mi = 0; mi < 4; ++mi)
        #pragma unroll
        for (int r = 0; r < 4; ++r) {
            const int m = mt * 128 + mblk * 64 + mi * 16 + q * 4 + r;
            const float bb = b1[m], wc0 = w2[m];
            const float wc1 = (cout == 2) ? w2[Cc + m] : 0.0f;
            #pragma unroll
            for (int nj = 0; nj < 4; ++nj) {
                const float h = fmaxf(acc[mi][nj][r] + bb, 0.0f);
                p0[nj] = fmaf(wc0, h, p0[nj]);
                p1[nj] = fmaf(wc1, h, p1[nj]);
            }
        }

    #pragma unroll
    for (int nj = 0; nj < 4; ++nj) {
        const int n = nblk * 64 + nj * 16 + n16;
        Red[n][0][mblk * 4 + q] = p0[nj];
        Red[n][1][mblk * 4 + q] = p1[nj];
    }
    __syncthreads();

    if (t < cout * 128) {
        const int n = t & 127, c = t >> 7;
        float sv = b2[c];
        #pragma unroll
        for (int i = 0; i < 8; ++i) sv += Red[n][c][i];
        if (head < 2) sv = sigclip(sv);
        const int xg = x0 + (n & 63);
        const int yg = y0 + (n >> 6);
        if (xg < Ww) out[outoff + c * HW + yg * Ww + xg] = sv;
    }
}

// ---------------------------------------------------------------------------
// Fallback conv (green, slow) if ws too small for the fast path.
// ---------------------------------------------------------------------------
__global__ __launch_bounds__(256) void conv_head_simple(
    const float* __restrict__ x,
    const float* __restrict__ w1, const float* __restrict__ b1,
    const float* __restrict__ w2, const float* __restrict__ b2,
    float* __restrict__ out, int outoff, int cout, int apply_sig)
{
    const int px = threadIdx.x & 63;
    const int g  = threadIdx.x >> 6;
    const int x0 = blockIdx.x * 64;
    const int y  = blockIdx.y;
    const int xg = x0 + px;
    __shared__ float RedS[4][64][2];

    bool valid[9]; int xoff[9];
    #pragma unroll
    for (int dy = 0; dy < 3; ++dy) {
        const int yy = y + dy - 1;
        #pragma unroll
        for (int dx = 0; dx < 3; ++dx) {
            const int xx = xg + dx - 1;
            const int k = dy * 3 + dx;
            valid[k] = (yy >= 0 && yy < Hh && xx >= 0 && xx < Ww);
            xoff[k]  = valid[k] ? (yy * Ww + xx) : 0;
        }
    }
    float hid[64];
    #pragma unroll
    for (int mi = 0; mi < 64; ++mi) hid[mi] = b1[g * 64 + mi];
    for (int ci = 0; ci < Cc; ++ci) {
        const float* xch = x + (size_t)ci * HW;
        float xv[9];
        #pragma unroll
        for (int k = 0; k < 9; ++k) xv[k] = valid[k] ? xch[xoff[k]] : 0.0f;
        const float* wci = w1 + ((size_t)(g * 64) * Cc + ci) * 9;
        #pragma unroll 8
        for (int mi = 0; mi < 64; ++mi) {
            const float* wr = wci + (size_t)mi * (Cc * 9);
            float h = hid[mi];
            #pragma unroll
            for (int k = 0; k < 9; ++k) h = fmaf(wr[k], xv[k], h);
            hid[mi] = h;
        }
    }
    float p0 = 0.f, p1 = 0.f;
    #pragma unroll 8
    for (int mi = 0; mi < 64; ++mi) {
        const int m = g * 64 + mi;
        const float h = fmaxf(hid[mi], 0.0f);
        p0 = fmaf(w2[m], h, p0);
        if (cout == 2) p1 = fmaf(w2[Cc + m], h, p1);
    }
    RedS[g][px][0] = p0; RedS[g][px][1] = p1;
    __syncthreads();
    if (g == 0 && xg < Ww)
        for (int c = 0; c < cout; ++c) {
            float sv = b2[c] + RedS[0][px][c] + RedS[1][px][c]
                             + RedS[2][px][c] + RedS[3][px][c];
            if (apply_sig) sv = sigclip(sv);
            out[outoff + c * HW + y * Ww + xg] = sv;
        }
}

// ---------------------------------------------------------------------------
// Decode (green): reads [HW,6HW), writes [6HW,14HW).
// ---------------------------------------------------------------------------
__global__ __launch_bounds__(256) void finalize_decode(float* __restrict__ out)
{
    const int i = blockIdx.x * 256 + threadIdx.x;
    if (i >= HW) return;
    const int h = i / Ww;
    const int w = i - h * Ww;

    const float k0 = out[HW + i];
    const float km = (w > 0)      ? out[HW + i - 1] : -1e30f;
    const float kp = (w < Ww - 1) ? out[HW + i + 1] : -1e30f;
    const float hmax = fmaxf(km, fmaxf(k0, kp));
    const float heat = (hmax == k0) ? k0 : 0.0f;

    const float off0 = out[2 * HW + i];
    const float off1 = out[3 * HW + i];
    const float reg0 = out[4 * HW + i];
    const float reg1 = out[5 * HW + i];
    const bool kmask = heat > 0.4f;

    out[6 * HW + i] = heat;
    out[7 * HW + w * Hh + h] = (off1 < 1.0f && kmask) ? 1.0f : 0.0f;
    out[8 * HW + 2 * i]      = (float)w + off0;
    out[8 * HW + 2 * i + 1]  = (float)h + off1;
    out[10 * HW + 2 * i]     = (float)w + reg0;
    out[10 * HW + 2 * i + 1] = (float)h + reg1;
    const float kb = kmask ? 1.0f : 0.0f;
    out[12 * HW + 2 * i]     = kb;
    out[12 * HW + 2 * i + 1] = kb;
}

// ---------------------------------------------------------------------------
extern "C" void kernel_launch(void* const* d_in, const int* in_sizes, int n_in,
                              void* d_out, int out_size, void* d_ws, size_t ws_size,
                              hipStream_t stream) {
    (void)in_sizes; (void)n_in; (void)out_size;
    const float* x = (const float*)d_in[0];
    float* out = (float*)d_out;

    if (ws_size >= (size_t)WS_NEED) {
        u16* Wa2      = (u16*)d_ws;
        u16* xt_alloc = Wa2 + WA2_U16;        // 16B-aligned
        u16* xt       = xt_alloc + GUARD;     // xt[p*256 + ci], p in [0,HW)

        prep_weights<<<dim3(288), 256, 0, stream>>>(
            (const float*)d_in[1], (const float*)d_in[5],
            (const float*)d_in[9], (const float*)d_in[13], Wa2);
        prep_x<<<dim3(250), 256, 0, stream>>>(x, (u32*)xt);
        prep_guard<<<dim3(64), 256, 0, stream>>>(
            (uint4*)xt_alloc, (uint4*)(xt + (size_t)HW * 256));

        conv_mfma<<<dim3(7, 80, 8), 256, 0, stream>>>(
            Wa2, xt,
            (const float*)d_in[2],  (const float*)d_in[6],
            (const float*)d_in[10], (const float*)d_in[14],
            (const float*)d_in[3],  (const float*)d_in[7],
            (const float*)d_in[11], (const float*)d_in[15],
            (const float*)d_in[4],  (const float*)d_in[8],
            (const float*)d_in[12], (const float*)d_in[16],
            out);
    } else {
        const int outoffs[4] = {0, HW, 2 * HW, 4 * HW};
        const int couts[4]   = {1, 1, 2, 2};
        for (int hd = 0; hd < 4; ++hd)
            conv_head_simple<<<dim3(7, 160), 256, 0, stream>>>(
                x,
                (const float*)d_in[1 + 4 * hd], (const float*)d_in[2 + 4 * hd],
                (const float*)d_in[3 + 4 * hd], (const float*)d_in[4 + 4 * hd],
                out, outoffs[hd], couts[hd], (hd < 2) ? 1 : 0);
    }
    finalize_decode<<<dim3(250), 256, 0, stream>>>(out);
}